// Round 2
// baseline (1269.186 us; speedup 1.0000x reference)
//
#include <hip/hip_runtime.h>

#define DZ 64
#define DX 32
#define DS 16
#define TT 1024
#define NS 1024

__device__ __forceinline__ float softplus_eps(float x) {
    // jax.nn.softplus = max(x,0) + log1p(exp(-|x|)); +1e-6
    return fmaxf(x, 0.f) + log1pf(expf(-fabsf(x))) + 1e-6f;
}

// ---------------- Phase 1: sequential z rollout ----------------
// 1024 waves, one per sim. lane = z-dim. LDS used only to broadcast
// relu(z_t) within the wave (wave-private slice, no __syncthreads).
__global__ __launch_bounds__(256, 1) void plrnn_z_kernel(
    const float* __restrict__ u,   // (T, N, 16)
    const float* __restrict__ z0,  // (N, 64)
    const float* __restrict__ nz,  // (T, N, 64)
    const float* __restrict__ AW,  // (64, 64)
    const float* __restrict__ Cm,  // (64, 16)
    const float* __restrict__ Q,   // (64,)
    float* __restrict__ zo)        // (T, N, 64)
{
    const int lane = threadIdx.x & 63;
    const int wv   = threadIdx.x >> 6;
    // wave-uniform sim id -> SGPR, so all stream bases become scalar
    const int sim  = __builtin_amdgcn_readfirstlane((int)((blockIdx.x << 2) | wv));

    __shared__ float lz[4][DZ];   // relu(z_t), one slice per wave

    // persistent per-lane weights
    float Wrow[DZ];
    #pragma unroll
    for (int k = 0; k < DZ; ++k) {
        float w = AW[lane * DZ + k];
        Wrow[k] = (k == lane) ? 0.f : w;   // zero diagonal
    }
    const float Ad = AW[lane * DZ + lane];
    float Crow[DS];
    #pragma unroll
    for (int s = 0; s < DS; ++s) Crow[s] = Cm[lane * DS + s];
    const float qv = softplus_eps(Q[lane]);

    float zl = z0[(size_t)sim * DZ + lane];

    const float*  pnz = nz + (size_t)sim * DZ + lane;
    const float4* pu  = (const float4*)(u + (size_t)sim * DS);  // wave-uniform address
    float*        pz  = zo + (size_t)sim * DZ + lane;

    const size_t snz = (size_t)NS * DZ;        // per-step element stride (z/nz)
    const size_t su4 = (size_t)NS * DS / 4;    // per-step float4 stride (u)

    lz[wv][lane] = fmaxf(zl, 0.f);

    // prefetch: nz depth 4, u depth 2 (alternating compile-time buffers)
    float nzb[4];
    #pragma unroll
    for (int j = 0; j < 4; ++j) nzb[j] = pnz[(size_t)j * snz];
    float4 ub[2][4];
    #pragma unroll
    for (int j = 0; j < 2; ++j) {
        #pragma unroll
        for (int q = 0; q < 4; ++q) ub[j][q] = pu[(size_t)j * su4 + q];
    }

    for (int t0 = 0; t0 < TT; t0 += 4) {
        #pragma unroll
        for (int j = 0; j < 4; ++j) {
            const int t = t0 + j;
            const float vnz = nzb[j];

            // emit z_t (scan outputs carry BEFORE update; z[0] == z0)
            pz[(size_t)t * snz] = zl;

            // u-dot (fills LDS latency shadow; u regs prefetched 2 steps ago)
            float m0 = Ad * zl, m1 = 0.f, m2 = 0.f, m3 = 0.f;
            {
                const float4 u0 = ub[j & 1][0], u1 = ub[j & 1][1];
                const float4 u2 = ub[j & 1][2], u3 = ub[j & 1][3];
                m0 = fmaf(Crow[ 0], u0.x, m0); m1 = fmaf(Crow[ 1], u0.y, m1);
                m2 = fmaf(Crow[ 2], u0.z, m2); m3 = fmaf(Crow[ 3], u0.w, m3);
                m0 = fmaf(Crow[ 4], u1.x, m0); m1 = fmaf(Crow[ 5], u1.y, m1);
                m2 = fmaf(Crow[ 6], u1.z, m2); m3 = fmaf(Crow[ 7], u1.w, m3);
                m0 = fmaf(Crow[ 8], u2.x, m0); m1 = fmaf(Crow[ 9], u2.y, m1);
                m2 = fmaf(Crow[10], u2.z, m2); m3 = fmaf(Crow[11], u2.w, m3);
                m0 = fmaf(Crow[12], u3.x, m0); m1 = fmaf(Crow[13], u3.y, m1);
                m2 = fmaf(Crow[14], u3.z, m2); m3 = fmaf(Crow[15], u3.w, m3);
            }

            // refill prefetch buffers (clamped at tail; values unused then)
            {
                const int tu = (t + 2 < TT) ? (t + 2) : (TT - 1);
                #pragma unroll
                for (int q = 0; q < 4; ++q) ub[j & 1][q] = pu[(size_t)tu * su4 + q];
                const int tn = (t + 4 < TT) ? (t + 4) : (TT - 1);
                nzb[j] = pnz[(size_t)tn * snz];
            }

            // W-dot: broadcast reads of relu(z_t) from the wave's LDS slice
            #pragma unroll
            for (int k = 0; k < DZ; k += 4) {
                const float4 zz = *(const float4*)&lz[wv][k];
                m0 = fmaf(Wrow[k + 0], zz.x, m0);
                m1 = fmaf(Wrow[k + 1], zz.y, m1);
                m2 = fmaf(Wrow[k + 2], zz.z, m2);
                m3 = fmaf(Wrow[k + 3], zz.w, m3);
            }

            // z_{t+1} = mu + nz*q ; publish relu for next step
            zl = fmaf(vnz, qv, (m0 + m1) + (m2 + m3));
            lz[wv][lane] = fmaxf(zl, 0.f);
        }
    }
}

// ---------------- Phase 2: x emission (fully parallel) ----------------
// x[row, p] = sum_k z[row, k] * B[p, k] + nx[row, p] * r[p]
// lane = (p = lane&31, k-half = lane>>5); one row per wave-iteration.
__global__ __launch_bounds__(256, 2) void plrnn_x_kernel(
    const float* __restrict__ z,    // (T*N, 64)
    const float* __restrict__ nx,   // (T*N, 32)
    const float* __restrict__ Bm,   // (32, 64)
    const float* __restrict__ R,    // (32,)
    float* __restrict__ xo)         // (T*N, 32)
{
    const int lane = threadIdx.x & 63;
    const int p    = lane & 31;
    const int kb   = (lane >> 5) << 5;   // 0 or 32

    float Brow[32];
    #pragma unroll
    for (int k = 0; k < 32; ++k) Brow[k] = Bm[p * DZ + kb + k];
    const float rv = softplus_eps(R[p]);

    const int gw = blockIdx.x * (blockDim.x >> 6) + (threadIdx.x >> 6);
    const int nw = gridDim.x * (blockDim.x >> 6);
    const int NR = TT * NS;

    for (int row = gw; row < NR; row += nw) {
        const float* zr = z + (size_t)row * DZ + kb;
        float a0 = 0.f, a1 = 0.f, a2 = 0.f, a3 = 0.f;
        #pragma unroll
        for (int k = 0; k < 32; k += 4) {
            const float4 zz = *(const float4*)(zr + k);
            a0 = fmaf(Brow[k + 0], zz.x, a0);
            a1 = fmaf(Brow[k + 1], zz.y, a1);
            a2 = fmaf(Brow[k + 2], zz.z, a2);
            a3 = fmaf(Brow[k + 3], zz.w, a3);
        }
        float s = (a0 + a1) + (a2 + a3);
        s += __shfl_xor(s, 32);                       // combine k-halves
        const float v = fmaf(nx[(size_t)row * DX + p], rv, s);
        if (lane < 32) xo[(size_t)row * DX + p] = v;
    }
}

extern "C" void kernel_launch(void* const* d_in, const int* in_sizes, int n_in,
                              void* d_out, int out_size, void* d_ws, size_t ws_size,
                              hipStream_t stream) {
    const float* u_  = (const float*)d_in[0];
    const float* z0_ = (const float*)d_in[1];
    const float* nz_ = (const float*)d_in[2];
    const float* nx_ = (const float*)d_in[3];
    const float* AW_ = (const float*)d_in[4];
    const float* C_  = (const float*)d_in[5];
    const float* B_  = (const float*)d_in[6];
    const float* Q_  = (const float*)d_in[7];
    const float* R_  = (const float*)d_in[8];

    float* zo = (float*)d_out;                 // (T,N,64) first
    float* xo = zo + (size_t)TT * NS * DZ;     // then (T,N,32)

    hipLaunchKernelGGL(plrnn_z_kernel, dim3(NS / 4), dim3(256), 0, stream,
                       u_, z0_, nz_, AW_, C_, Q_, zo);
    hipLaunchKernelGGL(plrnn_x_kernel, dim3(2048), dim3(256), 0, stream,
                       zo, nx_, B_, R_, xo);
}

// Round 3
// 941.257 us; speedup vs baseline: 1.3484x; 1.3484x over previous
//
#include <hip/hip_runtime.h>

#define DZ 64
#define DX 32
#define DS 16
#define TT 1024
#define NS 1024

__device__ __forceinline__ float softplus_eps(float x) {
    // jax.nn.softplus = max(x,0) + log1p(exp(-|x|)); +1e-6
    return fmaxf(x, 0.f) + log1pf(expf(-fabsf(x))) + 1e-6f;
}

// ---------------- Phase 1: sequential z rollout ----------------
// 1024 waves, one per sim, lane = z-dim. NO LDS: relu(z) is broadcast
// through SGPRs via v_readlane (per-SIMD VALU, no cross-wave contention).
__global__ __launch_bounds__(256, 1) void plrnn_z_kernel(
    const float* __restrict__ u,   // (T, N, 16)
    const float* __restrict__ z0,  // (N, 64)
    const float* __restrict__ nz,  // (T, N, 64)
    const float* __restrict__ AW,  // (64, 64)
    const float* __restrict__ Cm,  // (64, 16)
    const float* __restrict__ Q,   // (64,)
    float* __restrict__ zo)        // (T, N, 64)
{
    const int lane = threadIdx.x & 63;
    const int wv   = threadIdx.x >> 6;
    const int sim  = __builtin_amdgcn_readfirstlane((int)((blockIdx.x << 2) | wv));

    // persistent per-lane weights
    float Wrow[DZ];
    #pragma unroll
    for (int k = 0; k < DZ; ++k) {
        float w = AW[lane * DZ + k];
        Wrow[k] = (k == lane) ? 0.f : w;   // zero diagonal
    }
    float Ad = AW[lane * DZ + lane];
    float Crow[DS];
    #pragma unroll
    for (int s = 0; s < DS; ++s) Crow[s] = Cm[lane * DS + s];
    float qv = softplus_eps(Q[lane]);

    // Pin weights in VGPRs: opaque asm def -> allocator cannot remat the
    // global loads into the hot loop (R2 regression: VGPR_Count=64, spilled).
    #pragma unroll
    for (int k = 0; k < DZ; ++k) asm volatile("" : "+v"(Wrow[k]));
    #pragma unroll
    for (int s = 0; s < DS; ++s) asm volatile("" : "+v"(Crow[s]));
    asm volatile("" : "+v"(Ad));
    asm volatile("" : "+v"(qv));

    float zl = z0[(size_t)sim * DZ + lane];

    const float*  pnz = nz + (size_t)sim * DZ + lane;
    const float4* pu  = (const float4*)(u + (size_t)sim * DS);  // wave-uniform
    float*        pz  = zo + (size_t)sim * DZ + lane;

    const size_t snz = (size_t)NS * DZ;        // per-step element stride
    const size_t su4 = (size_t)NS * DS / 4;    // per-step float4 stride (u)

    // prefetch: nz depth 4, u depth 2
    float nzb[4];
    #pragma unroll
    for (int j = 0; j < 4; ++j) nzb[j] = pnz[(size_t)j * snz];
    float4 ub[2][4];
    #pragma unroll
    for (int j = 0; j < 2; ++j)
        #pragma unroll
        for (int q = 0; q < 4; ++q) ub[j][q] = pu[(size_t)j * su4 + q];

    for (int t0 = 0; t0 < TT; t0 += 4) {
        #pragma unroll
        for (int j = 0; j < 4; ++j) {
            const int t = t0 + j;
            const float vnz = nzb[j];

            // emit z_t (carry BEFORE update; z[0] == z0)
            pz[(size_t)t * snz] = zl;

            const int rzb = __float_as_int(fmaxf(zl, 0.f));

            float m0 = Ad * zl, m1 = 0.f, m2 = 0.f, m3 = 0.f;

            // u-dot (operands prefetched 2 steps ago)
            {
                const float4 u0 = ub[j & 1][0], u1 = ub[j & 1][1];
                const float4 u2 = ub[j & 1][2], u3 = ub[j & 1][3];
                m0 = fmaf(Crow[ 0], u0.x, m0); m1 = fmaf(Crow[ 1], u0.y, m1);
                m2 = fmaf(Crow[ 2], u0.z, m2); m3 = fmaf(Crow[ 3], u0.w, m3);
                m0 = fmaf(Crow[ 4], u1.x, m0); m1 = fmaf(Crow[ 5], u1.y, m1);
                m2 = fmaf(Crow[ 6], u1.z, m2); m3 = fmaf(Crow[ 7], u1.w, m3);
                m0 = fmaf(Crow[ 8], u2.x, m0); m1 = fmaf(Crow[ 9], u2.y, m1);
                m2 = fmaf(Crow[10], u2.z, m2); m3 = fmaf(Crow[11], u2.w, m3);
                m0 = fmaf(Crow[12], u3.x, m0); m1 = fmaf(Crow[13], u3.y, m1);
                m2 = fmaf(Crow[14], u3.z, m2); m3 = fmaf(Crow[15], u3.w, m3);
            }

            // refill prefetch (clamped at tail; values unused then)
            {
                const int tu = (t + 2 < TT) ? (t + 2) : (TT - 1);
                #pragma unroll
                for (int q = 0; q < 4; ++q) ub[j & 1][q] = pu[(size_t)tu * su4 + q];
                const int tn = (t + 4 < TT) ? (t + 4) : (TT - 1);
                nzb[j] = pnz[(size_t)tn * snz];
            }

            // W-dot: broadcast relu(z) through SGPRs (readlane), chunks of 8
            #pragma unroll
            for (int c = 0; c < DZ; c += 8) {
                const float s0 = __int_as_float(__builtin_amdgcn_readlane(rzb, c + 0));
                const float s1 = __int_as_float(__builtin_amdgcn_readlane(rzb, c + 1));
                const float s2 = __int_as_float(__builtin_amdgcn_readlane(rzb, c + 2));
                const float s3 = __int_as_float(__builtin_amdgcn_readlane(rzb, c + 3));
                const float s4 = __int_as_float(__builtin_amdgcn_readlane(rzb, c + 4));
                const float s5 = __int_as_float(__builtin_amdgcn_readlane(rzb, c + 5));
                const float s6 = __int_as_float(__builtin_amdgcn_readlane(rzb, c + 6));
                const float s7 = __int_as_float(__builtin_amdgcn_readlane(rzb, c + 7));
                m0 = fmaf(Wrow[c + 0], s0, m0);
                m1 = fmaf(Wrow[c + 1], s1, m1);
                m2 = fmaf(Wrow[c + 2], s2, m2);
                m3 = fmaf(Wrow[c + 3], s3, m3);
                m0 = fmaf(Wrow[c + 4], s4, m0);
                m1 = fmaf(Wrow[c + 5], s5, m1);
                m2 = fmaf(Wrow[c + 6], s6, m2);
                m3 = fmaf(Wrow[c + 7], s7, m3);
            }

            // z_{t+1} = mu + nz*q
            zl = fmaf(vnz, qv, (m0 + m1) + (m2 + m3));
        }
    }
}

// ---------------- Phase 2: x emission (fully parallel) ----------------
// One wave handles 2 rows per iteration: lanes 0-31 -> row e, lanes 32-63
// -> row e+1; each lane computes one x[row, p] summing all 64 k.
// Fully coalesced 256B loads/stores, no shuffles, no guards.
__global__ __launch_bounds__(256, 4) void plrnn_x_kernel(
    const float* __restrict__ z,    // (T*N, 64)
    const float* __restrict__ nx,   // (T*N, 32)
    const float* __restrict__ Bm,   // (32, 64)
    const float* __restrict__ R,    // (32,)
    float* __restrict__ xo)         // (T*N, 32)
{
    const int lane = threadIdx.x & 63;
    const int p    = lane & 31;

    float Brow[DZ];                 // B[p, 0..63]
    #pragma unroll
    for (int k = 0; k < DZ; ++k) Brow[k] = Bm[p * DZ + k];
    #pragma unroll
    for (int k = 0; k < DZ; ++k) asm volatile("" : "+v"(Brow[k]));
    const float rv = softplus_eps(R[p]);

    const int gw   = blockIdx.x * 4 + (threadIdx.x >> 6);   // global wave id
    const int base = gw * 128;                              // 1M rows / 8192 waves

    for (int i = 0; i < 128; i += 4) {
        const int e0 = base + i + (lane >> 5);      // rows i, i+1
        const int e1 = e0 + 2;                      // rows i+2, i+3
        const float* z0p = z + (size_t)e0 * DZ;
        const float* z1p = z + (size_t)e1 * DZ;
        const float n0 = nx[(size_t)e0 * DX + p];
        const float n1 = nx[(size_t)e1 * DX + p];

        float a0 = 0.f, a1 = 0.f, a2 = 0.f, a3 = 0.f;
        float b0 = 0.f, b1 = 0.f, b2 = 0.f, b3 = 0.f;
        #pragma unroll
        for (int k = 0; k < DZ; k += 4) {
            const float4 x0 = *(const float4*)(z0p + k);
            const float4 x1 = *(const float4*)(z1p + k);
            a0 = fmaf(Brow[k + 0], x0.x, a0);
            a1 = fmaf(Brow[k + 1], x0.y, a1);
            a2 = fmaf(Brow[k + 2], x0.z, a2);
            a3 = fmaf(Brow[k + 3], x0.w, a3);
            b0 = fmaf(Brow[k + 0], x1.x, b0);
            b1 = fmaf(Brow[k + 1], x1.y, b1);
            b2 = fmaf(Brow[k + 2], x1.z, b2);
            b3 = fmaf(Brow[k + 3], x1.w, b3);
        }
        xo[(size_t)e0 * DX + p] = fmaf(n0, rv, (a0 + a1) + (a2 + a3));
        xo[(size_t)e1 * DX + p] = fmaf(n1, rv, (b0 + b1) + (b2 + b3));
    }
}

extern "C" void kernel_launch(void* const* d_in, const int* in_sizes, int n_in,
                              void* d_out, int out_size, void* d_ws, size_t ws_size,
                              hipStream_t stream) {
    const float* u_  = (const float*)d_in[0];
    const float* z0_ = (const float*)d_in[1];
    const float* nz_ = (const float*)d_in[2];
    const float* nx_ = (const float*)d_in[3];
    const float* AW_ = (const float*)d_in[4];
    const float* C_  = (const float*)d_in[5];
    const float* B_  = (const float*)d_in[6];
    const float* Q_  = (const float*)d_in[7];
    const float* R_  = (const float*)d_in[8];

    float* zo = (float*)d_out;                 // (T,N,64) first
    float* xo = zo + (size_t)TT * NS * DZ;     // then (T,N,32)

    hipLaunchKernelGGL(plrnn_z_kernel, dim3(NS / 4), dim3(256), 0, stream,
                       u_, z0_, nz_, AW_, C_, Q_, zo);
    hipLaunchKernelGGL(plrnn_x_kernel, dim3(2048), dim3(256), 0, stream,
                       zo, nx_, B_, R_, xo);
}